// Round 14
// baseline (269.676 us; speedup 1.0000x reference)
//
#include <hip/hip_runtime.h>
#include <math.h>

#define HC 128
#define GG 64
#define NEG 0.2f
#define TILE 8192
#define BW 128          // nodes per bucket
#define SLOT 8192       // staging slots per bucket (max bucket load ~4600)
#define NBMAX 512
#define LDA 136         // As LDS stride in bf16 elems
#define PPARTS 8        // pool partial slots per graph

typedef __attribute__((ext_vector_type(8))) short short8;
typedef __attribute__((ext_vector_type(4))) float floatx4;
typedef __attribute__((ext_vector_type(2))) float floatx2;

static __device__ __forceinline__ float leaky(float x) { return x > 0.f ? x : NEG * x; }

static __device__ __forceinline__ unsigned short f2bf(float f) {
    unsigned u = __float_as_uint(f);
    u += 0x7FFF + ((u >> 16) & 1);          // round-nearest-even
    return (unsigned short)(u >> 16);
}
static __device__ __forceinline__ float bf2f(unsigned short s) {
    return __uint_as_float(((unsigned)s) << 16);
}

// ---- fp8 e4m3 (OCP) helpers ----
#if __has_builtin(__builtin_amdgcn_cvt_pk_f32_fp8) && __has_builtin(__builtin_amdgcn_cvt_pk_fp8_f32)
template <bool HI>
static __device__ __forceinline__ floatx2 fp8pair(unsigned int w) {
    return __builtin_amdgcn_cvt_pk_f32_fp8((int)w, HI);
}
static __device__ __forceinline__ unsigned int f32x2_fp8(float a, float b) {
    return ((unsigned int)__builtin_amdgcn_cvt_pk_fp8_f32(a, b, 0, false)) & 0xFFFFu;
}
#else
static __device__ __forceinline__ float fp8one(unsigned v) {
    unsigned e = (v >> 3) & 15u, m = v & 7u;
    float mag = e ? __uint_as_float(((e + 120u) << 23) | (m << 20))
                  : (float)m * 0.001953125f;
    return (v & 0x80u) ? -mag : mag;
}
template <bool HI>
static __device__ __forceinline__ floatx2 fp8pair(unsigned int w) {
    unsigned h = HI ? (w >> 16) : w;
    floatx2 r; r.x = fp8one(h & 0xFFu); r.y = fp8one((h >> 8) & 0xFFu);
    return r;
}
static __device__ __forceinline__ unsigned fp8enc(float f) {
    unsigned u = __float_as_uint(f);
    unsigned s = (u >> 24) & 0x80u;
    float a = fabsf(f);
    if (a >= 448.f) return s | 0x7Eu;
    if (a < 0.015625f) {
        unsigned m = (unsigned)(int)rintf(a * 512.f);
        return s | m;
    }
    u = __float_as_uint(a);
    u += 0xFFFFFu + ((u >> 20) & 1u);
    unsigned e8 = (u >> 23) - 120u;
    if (e8 >= 16u) return s | 0x7Eu;
    return s | (e8 << 3) | ((u >> 20) & 7u);
}
static __device__ __forceinline__ unsigned int f32x2_fp8(float a, float b) {
    return fp8enc(a) | (fp8enc(b) << 8);
}
#endif

// accumulate one fp8 row (16 ch) weighted by w into acc[8] (floatx2)
static __device__ __forceinline__ void acc16(floatx2* acc, float w, const uint4& d) {
    floatx2 w2 = {w, w};
    acc[0] += w2 * fp8pair<false>(d.x);
    acc[1] += w2 * fp8pair<true>(d.x);
    acc[2] += w2 * fp8pair<false>(d.y);
    acc[3] += w2 * fp8pair<true>(d.y);
    acc[4] += w2 * fp8pair<false>(d.z);
    acc[5] += w2 * fp8pair<true>(d.z);
    acc[6] += w2 * fp8pair<false>(d.w);
    acc[7] += w2 * fp8pair<true>(d.w);
}

// ---------------- setup: gbcur bases + prep_w + bounds + row_start[Nn] ----------------
__global__ __launch_bounds__(256) void setup_k(const float* __restrict__ W1,
                                               const float* __restrict__ W2,
                                               unsigned short* __restrict__ Wt1,
                                               unsigned short* __restrict__ Wt2,
                                               int* __restrict__ gbcur,
                                               const int* __restrict__ batch,
                                               int* __restrict__ node_end,
                                               int* __restrict__ row_start,
                                               int NB, int Nn, int M) {
    int i = blockIdx.x * 256 + threadIdx.x;
    if (i < NB) gbcur[i] = i * SLOT;
    if (i == 0) row_start[Nn] = M;
    if (i < 32768) {
        // W (fp32 [k][n]) -> bf16 in MFMA A-fragment order
        const float* W = (i >> 14) ? W2 : W1;
        unsigned short* Wt = (i >> 14) ? Wt2 : Wt1;
        int d = i & 16383;
        int j = d & 7;
        int m = (d >> 3) & 15;
        int qf = d >> 7;
        int q = qf & 3;
        int f = qf >> 2;
        int kb = f & 3;
        int ct = f >> 2;
        int n = ct * 16 + m;
        int k = kb * 32 + q * 8 + j;
        Wt[d] = f2bf(W[k * 128 + n]);
    }
    if (i < Nn) {
        int b = batch[i];
        if (i == 0) {
            for (int g = 0; g < b; g++) node_end[g] = 0;
        }
        int bn = (i + 1 < Nn) ? batch[i + 1] : GG;
        for (int g = b; g < bn; g++) node_end[g] = i + 1;
    }
}

// ---------------- phase 1: LDS-binned scatter into fixed bucket slots ----------------
__global__ __launch_bounds__(256) void binscat_k(const int* __restrict__ ei,
                                                 int* __restrict__ gbcur,
                                                 unsigned int* __restrict__ staging,
                                                 int E, int M, int NB) {
    __shared__ unsigned int reorder[TILE];
    __shared__ int s_cnt[NBMAX], s_off[NBMAX], s_run[NBMAX];
    __shared__ int s_wsum[8];
    __shared__ int s_carry;
    const int tid = threadIdx.x;
    const int lane = tid & 63, wid = tid >> 6;
    const int tbase = blockIdx.x * TILE;
    const int tcnt = min(TILE, M - tbase);

    for (int i = tid; i < NB; i += 256) s_cnt[i] = 0;
    if (tid == 0) s_carry = 0;
    __syncthreads();

    for (int t = tid; t < tcnt; t += 256) {
        int i = tbase + t;
        int dst = (i < E) ? ei[E + i] : (i - E);
        atomicAdd(&s_cnt[dst >> 7], 1);
    }
    __syncthreads();

    // exclusive scan s_cnt -> s_off
    for (int base = 0; base < NB; base += 256) {
        int i = base + tid;
        int v = (i < NB) ? s_cnt[i] : 0;
        int incl = v;
        #pragma unroll
        for (int off = 1; off < 64; off <<= 1) {
            int u = __shfl_up(incl, off);
            if (lane >= off) incl += u;
        }
        if (lane == 63) s_wsum[wid] = incl;
        __syncthreads();
        if (tid == 0) {
            int a = 0;
            for (int w = 0; w < 4; w++) { int tv = s_wsum[w]; s_wsum[w] = a; a += tv; }
            s_wsum[4] = a;
        }
        __syncthreads();
        int excl = s_carry + s_wsum[wid] + incl - v;
        if (i < NB) s_off[i] = excl;
        __syncthreads();
        if (tid == 0) s_carry += s_wsum[4];
        __syncthreads();
    }

    for (int b = tid; b < NB; b += 256)
        s_run[b] = atomicAdd(&gbcur[b], s_cnt[b]);
    for (int b = tid; b < NB; b += 256) s_cnt[b] = s_off[b];
    __syncthreads();

    for (int t = tid; t < tcnt; t += 256) {
        int i = tbase + t;
        int src, dst;
        if (i < E) { src = ei[i]; dst = ei[E + i]; }
        else       { src = dst = i - E; }
        unsigned int p = ((unsigned int)dst << 16) | (unsigned int)src;
        int r = atomicAdd(&s_cnt[dst >> 7], 1);
        reorder[r] = p;
    }
    __syncthreads();

    for (int t = tid; t < tcnt; t += 256) {
        unsigned int p = reorder[t];
        int b = p >> 23;                        // dst >> 7
        staging[s_run[b] + (t - s_off[b])] = p;
    }
}

// ---------------- phase 2: bucket-base reduce + local scan -> row_start + srcs --------
__global__ __launch_bounds__(256) void unbin_k(const unsigned int* __restrict__ staging,
                                               const int* __restrict__ gbcur,
                                               int* __restrict__ row_start,
                                               unsigned short* __restrict__ srcs, int Nn) {
    __shared__ int s_cnt[BW];
    __shared__ int s_cur[BW];
    __shared__ int s_w[4];
    int b = blockIdx.x, t = threadIdx.x;
    int sbase = b * SLOT;
    int cnt = gbcur[b] - sbase;

    // bucket base = sum of counts of buckets < b
    int pacc = 0;
    for (int i = t; i < b; i += 256) pacc += gbcur[i] - i * SLOT;
    #pragma unroll
    for (int off = 1; off < 64; off <<= 1) pacc += __shfl_xor(pacc, off);
    if ((t & 63) == 0) s_w[t >> 6] = pacc;
    __syncthreads();
    int bb = s_w[0] + s_w[1] + s_w[2] + s_w[3];
    __syncthreads();

    int n0 = b * BW;
    if (t < BW) s_cnt[t] = 0;
    __syncthreads();
    for (int j = t; j < cnt; j += 256)
        atomicAdd(&s_cnt[(staging[sbase + j] >> 16) & (BW - 1)], 1);
    __syncthreads();
    int v = (t < BW) ? s_cnt[t] : 0;
    int incl = v;
    #pragma unroll
    for (int off = 1; off < 64; off <<= 1) {
        int u = __shfl_up(incl, off);
        if ((t & 63) >= off) incl += u;
    }
    if (t < BW && (t & 63) == 63) s_w[t >> 6] = incl;
    __syncthreads();
    int excl = incl - v + ((t >= 64 && t < BW) ? s_w[0] : 0);
    if (t < BW) {
        s_cur[t] = bb + excl;
        if (n0 + t < Nn) row_start[n0 + t] = bb + excl;
    }
    __syncthreads();
    for (int j = t; j < cnt; j += 256) {
        unsigned int p = staging[sbase + j];
        int ln = (int)(p >> 16) & (BW - 1);
        int r = atomicAdd(&s_cur[ln], 1);
        srcs[r] = (unsigned short)(p & 0xFFFFu);
    }
}

// ---------------- fused MFMA GEMM + attention dots + fp8 quantize ----------------
__global__ __launch_bounds__(128) void gemm_fused(const void* __restrict__ Xv,
                                                  int x_f32,
                                                  const unsigned short* __restrict__ Wt,
                                                  const float* __restrict__ att_s,
                                                  const float* __restrict__ att_d,
                                                  unsigned char* __restrict__ H8,
                                                  float* __restrict__ a_src,
                                                  float* __restrict__ a_dst,
                                                  int n_rows) {
    __shared__ unsigned short As[64 * LDA];   // 17408 B
    __shared__ unsigned short Ws[16384];      // 32768 B, fragment order
    const int tid = threadIdx.x;
    const int row0 = blockIdx.x * 64;

    for (int i = tid; i < 2048; i += 128)
        ((uint4*)Ws)[i] = ((const uint4*)Wt)[i];
    if (x_f32) {
        const float* X = (const float*)Xv;
        for (int i = tid; i < 2048; i += 128) {
            int r = i >> 5;
            int c4 = (i & 31) << 2;
            int gr = row0 + r;
            float4 v = (gr < n_rows) ? ((const float4*)&X[(size_t)gr * 128])[i & 31]
                                     : make_float4(0.f, 0.f, 0.f, 0.f);
            ushort4 bv = {f2bf(v.x), f2bf(v.y), f2bf(v.z), f2bf(v.w)};
            *(ushort4*)&As[r * LDA + c4] = bv;
        }
    } else {
        const unsigned short* X = (const unsigned short*)Xv;
        for (int i = tid; i < 1024; i += 128) {
            int r = i >> 4;
            int c8 = (i & 15) << 3;
            int gr = row0 + r;
            uint4 v = (gr < n_rows) ? *(const uint4*)&X[(size_t)gr * 128 + c8]
                                    : make_uint4(0, 0, 0, 0);
            *(uint4*)&As[r * LDA + c8] = v;
        }
    }
    __syncthreads();

    const int lane = tid & 63;
    const int wave = tid >> 6;
    const int m = lane & 15;          // node-in-tile (C col)
    const int quad = lane >> 4;       // channel quad (C row group)
    const int wr0 = wave * 32;

    floatx4 acc[2][8];
    #pragma unroll
    for (int nt = 0; nt < 2; nt++)
        #pragma unroll
        for (int ct = 0; ct < 8; ct++)
            acc[nt][ct] = (floatx4){0.f, 0.f, 0.f, 0.f};

    #pragma unroll
    for (int kb = 0; kb < 4; kb++) {
        short8 x0 = *(const short8*)&As[(wr0 + m) * LDA + kb * 32 + quad * 8];
        short8 x1 = *(const short8*)&As[(wr0 + 16 + m) * LDA + kb * 32 + quad * 8];
        #pragma unroll
        for (int ct = 0; ct < 8; ct++) {
            short8 wf = *(const short8*)&Ws[(((ct * 4 + kb) * 4) + quad) * 128 + m * 8];
            acc[0][ct] = __builtin_amdgcn_mfma_f32_16x16x32_bf16(wf, x0, acc[0][ct], 0, 0, 0);
            acc[1][ct] = __builtin_amdgcn_mfma_f32_16x16x32_bf16(wf, x1, acc[1][ct], 0, 0, 0);
        }
    }

    const int q4 = quad * 4;
    #pragma unroll
    for (int nt = 0; nt < 2; nt++) {
        int node = row0 + wr0 + nt * 16 + m;
        bool vld = node < n_rows;
        float ps[4] = {0.f, 0.f, 0.f, 0.f};
        float pd[4] = {0.f, 0.f, 0.f, 0.f};
        #pragma unroll
        for (int ct = 0; ct < 8; ct++) {
            floatx4 v = acc[nt][ct];
            int c0 = ct * 16 + q4;
            float4 avs = *(const float4*)&att_s[c0];
            float4 avd = *(const float4*)&att_d[c0];
            int h = ct >> 1;
            ps[h] += v[0] * avs.x + v[1] * avs.y + v[2] * avs.z + v[3] * avs.w;
            pd[h] += v[0] * avd.x + v[1] * avd.y + v[2] * avd.z + v[3] * avd.w;
            if (vld) {
                unsigned pk01 = f32x2_fp8(v[0], v[1]);
                unsigned pk23 = f32x2_fp8(v[2], v[3]);
                *(unsigned*)&H8[(size_t)node * 128 + c0] = pk01 | (pk23 << 16);
            }
        }
        #pragma unroll
        for (int h = 0; h < 4; h++) {
            ps[h] += __shfl_xor(ps[h], 16); ps[h] += __shfl_xor(ps[h], 32);
            pd[h] += __shfl_xor(pd[h], 16); pd[h] += __shfl_xor(pd[h], 32);
        }
        if (lane < 16 && vld) {
            float4 s4 = {ps[0], ps[1], ps[2], ps[3]};
            float4 d4 = {pd[0], pd[1], pd[2], pd[3]};
            *(float4*)&a_src[node * 4] = s4;
            *(float4*)&a_dst[node * 4] = d4;
        }
    }
}

// ---------------- GAT aggregation: 8 lanes/node, fp8 gather, uint2 srcs x4 ----------
__global__ __launch_bounds__(256) void gat_agg(const unsigned char* __restrict__ H8,
                                               const float* __restrict__ a_src,
                                               const float* __restrict__ a_dst,
                                               const int* __restrict__ row_start,
                                               const unsigned short* __restrict__ srcs,
                                               const float* __restrict__ bias,
                                               unsigned short* __restrict__ OUT,
                                               int n_rows, int elu) {
    int n = (blockIdx.x * 256 + threadIdx.x) >> 3;
    if (n >= n_rows) return;
    int li = threadIdx.x & 7;
    int hd = li >> 1;
    int base = row_start[n];
    int end = row_start[n + 1];
    float adh = a_dst[n * 4 + hd];

    floatx2 acc[8];
    #pragma unroll
    for (int k = 0; k < 8; k++) acc[k] = (floatx2){0.f, 0.f};
    float wsum = 0.f;

    int j = base;
    // alignment prologue: advance j to a multiple of 4 (srcs 256B-aligned)
    int head_n = min(end - j, (4 - (base & 3)) & 3);
    for (int q = 0; q < head_n; q++, j++) {
        int s0 = srcs[j];
        float w0 = __expf(leaky(a_src[s0 * 4 + hd] + adh));
        uint4 d0 = *(const uint4*)&H8[(size_t)s0 * 128 + li * 16];
        acc16(acc, w0, d0);
        wsum += w0;
    }
    // main: 4 edges per iter, single 8B srcs load
    for (; j + 4 <= end; j += 4) {
        uint2 sv = *(const uint2*)&srcs[j];
        int s0 = sv.x & 0xFFFFu, s1 = sv.x >> 16;
        int s2 = sv.y & 0xFFFFu, s3 = sv.y >> 16;
        float a0 = a_src[s0 * 4 + hd];
        float a1 = a_src[s1 * 4 + hd];
        float a2 = a_src[s2 * 4 + hd];
        float a3 = a_src[s3 * 4 + hd];
        uint4 d0 = *(const uint4*)&H8[(size_t)s0 * 128 + li * 16];
        uint4 d1 = *(const uint4*)&H8[(size_t)s1 * 128 + li * 16];
        uint4 d2 = *(const uint4*)&H8[(size_t)s2 * 128 + li * 16];
        uint4 d3 = *(const uint4*)&H8[(size_t)s3 * 128 + li * 16];
        float w0 = __expf(leaky(a0 + adh));
        float w1 = __expf(leaky(a1 + adh));
        float w2 = __expf(leaky(a2 + adh));
        float w3 = __expf(leaky(a3 + adh));
        acc16(acc, w0, d0);
        acc16(acc, w1, d1);
        acc16(acc, w2, d2);
        acc16(acc, w3, d3);
        wsum += (w0 + w1) + (w2 + w3);
    }
    // tail
    for (; j < end; j++) {
        int s0 = srcs[j];
        float w0 = __expf(leaky(a_src[s0 * 4 + hd] + adh));
        uint4 d0 = *(const uint4*)&H8[(size_t)s0 * 128 + li * 16];
        acc16(acc, w0, d0);
        wsum += w0;
    }

    float ih = 1.0f / (wsum + 1e-16f);
    float o[16];
    #pragma unroll
    for (int k = 0; k < 8; k++) {
        float2 bv = *(const float2*)&bias[li * 16 + 2 * k];
        o[2 * k]     = acc[k].x * ih + bv.x;
        o[2 * k + 1] = acc[k].y * ih + bv.y;
    }
    if (elu) {
        #pragma unroll
        for (int k = 0; k < 16; k++) o[k] = o[k] > 0.f ? o[k] : __expf(o[k]) - 1.f;
    }
    unsigned int pk[8];
    #pragma unroll
    for (int k = 0; k < 8; k++)
        pk[k] = ((unsigned)f2bf(o[2 * k + 1]) << 16) | (unsigned)f2bf(o[2 * k]);
    uint4 s0v = {pk[0], pk[1], pk[2], pk[3]};
    uint4 s1v = {pk[4], pk[5], pk[6], pk[7]};
    unsigned short* op = &OUT[(size_t)n * 128 + li * 16];
    *(uint4*)op = s0v;
    *(uint4*)(op + 8) = s1v;
}

// ---------------- mean pool: atomic-free partial sums ----------------
__global__ __launch_bounds__(256) void pool_k(const unsigned* __restrict__ H2u,
                                              const int* __restrict__ node_end,
                                              float* __restrict__ partial) {
    __shared__ float ls[4][128];
    int g = blockIdx.x >> 3;
    int p = blockIdx.x & (PPARTS - 1);
    int s = (g > 0) ? node_end[g - 1] : 0;
    int e = node_end[g];
    int cnt = e - s;
    int chunk = (cnt + PPARTS - 1) >> 3;
    int n0 = s + p * chunk;
    int n1 = min(n0 + chunk, e);
    int col = threadIdx.x & 63;
    int nr = threadIdx.x >> 6;
    float ax = 0.f, ay = 0.f;
    for (int n = n0 + nr; n < n1; n += 4) {
        unsigned u = H2u[(size_t)n * 64 + col];
        ax += bf2f((unsigned short)(u & 0xFFFFu));
        ay += bf2f((unsigned short)(u >> 16));
    }
    ls[nr][col * 2] = ax;
    ls[nr][col * 2 + 1] = ay;
    __syncthreads();
    if (threadIdx.x < 128) {
        float v = ls[0][threadIdx.x] + ls[1][threadIdx.x] +
                  ls[2][threadIdx.x] + ls[3][threadIdx.x];
        partial[(size_t)(p * GG + g) * 128 + threadIdx.x] = v;
    }
}

// ---------------- final: sum partials, mean, fc + log_softmax ----------------
__global__ __launch_bounds__(64) void head_k(const float* __restrict__ partial,
                                             const int* __restrict__ node_end,
                                             const float* __restrict__ fcW,
                                             const float* __restrict__ fcb,
                                             float* __restrict__ out) {
    __shared__ float p[128];
    __shared__ float lg[8];
    int g = blockIdx.x, t = threadIdx.x;
    int c = node_end[g] - (g > 0 ? node_end[g - 1] : 0);
    float cnt = fmaxf((float)c, 1.0f);
    float v0 = 0.f, v1 = 0.f;
    #pragma unroll
    for (int q = 0; q < PPARTS; q++) {
        v0 += partial[(size_t)(q * GG + g) * 128 + t];
        v1 += partial[(size_t)(q * GG + g) * 128 + 64 + t];
    }
    p[t] = v0 / cnt;
    p[t + 64] = v1 / cnt;
    __syncthreads();
    if (t < 8) {
        float s = fcb[t];
        for (int k = 0; k < 128; k++) s += p[k] * fcW[k * 8 + t];
        lg[t] = s;
    }
    __syncthreads();
    if (t == 0) {
        float m = lg[0];
        for (int j = 1; j < 8; j++) m = fmaxf(m, lg[j]);
        float se = 0.f;
        for (int j = 0; j < 8; j++) se += expf(lg[j] - m);
        float lse = logf(se) + m;
        for (int j = 0; j < 8; j++) out[g * 8 + j] = lg[j] - lse;
    }
}

extern "C" void kernel_launch(void* const* d_in, const int* in_sizes, int n_in,
                              void* d_out, int out_size, void* d_ws, size_t ws_size,
                              hipStream_t stream) {
    const float* x    = (const float*)d_in[0];
    const int*   ei   = (const int*)d_in[1];
    const int*   batch= (const int*)d_in[2];
    const float* W1   = (const float*)d_in[3];
    const float* as1  = (const float*)d_in[4];
    const float* ad1  = (const float*)d_in[5];
    const float* b1   = (const float*)d_in[6];
    const float* W2   = (const float*)d_in[7];
    const float* as2  = (const float*)d_in[8];
    const float* ad2  = (const float*)d_in[9];
    const float* b2   = (const float*)d_in[10];
    const float* fcW  = (const float*)d_in[11];
    const float* fcb  = (const float*)d_in[12];
    float* out = (float*)d_out;

    const int Nn = in_sizes[0] / HC;       // 50000
    const int E  = in_sizes[1] / 2;        // 1600000
    const int M  = E + Nn;                 // edges incl. self loops
    const int NB = (Nn + BW - 1) / BW;     // 391 buckets

    char* ws = (char*)d_ws;
    size_t off = 0;
    auto alloc = [&](size_t bytes) -> char* {
        char* p = ws + off;
        off = (off + bytes + 255) & ~(size_t)255;
        return p;
    };
    size_t hB_bytes  = (size_t)Nn * HC * 2;     // bf16 node features
    size_t stg_bytes = (size_t)NB * SLOT * 4;   // CSR staging
    char* hB_region = alloc(hB_bytes > stg_bytes ? hB_bytes : stg_bytes);
    unsigned short* hB      = (unsigned short*)hB_region;     // bf16 agg out / gemm in
    unsigned int*   staging = (unsigned int*)hB_region;       // aliased: used before hB
    unsigned char*  H8      = (unsigned char*)alloc((size_t)Nn * HC);  // fp8 h
    float* asrc      = (float*)alloc((size_t)Nn * 4 * 4);
    float* adst      = (float*)alloc((size_t)Nn * 4 * 4);
    unsigned short* srcs = (unsigned short*)alloc((size_t)M * 2);
    int*   row_start = (int*)alloc((size_t)(Nn + 1) * 4);
    float* partial   = (float*)alloc((size_t)PPARTS * GG * HC * 4);
    int*   node_end  = (int*)alloc((size_t)GG * 4);
    int*   gbcur     = (int*)alloc((size_t)NB * 4);
    unsigned short* Wt1 = (unsigned short*)alloc(16384 * 2);
    unsigned short* Wt2 = (unsigned short*)alloc(16384 * 2);

    // 1. setup (gbcur bases + prep_w + bounds + row_start[Nn])
    setup_k<<<(Nn + 255) / 256, 256, 0, stream>>>(W1, W2, Wt1, Wt2, gbcur, batch,
                                                  node_end, row_start, NB, Nn, M);
    // 2. CSR build
    binscat_k<<<(M + TILE - 1) / TILE, 256, 0, stream>>>(ei, gbcur, staging, E, M, NB);
    unbin_k<<<NB, 256, 0, stream>>>(staging, gbcur, row_start, srcs, Nn);
    // 3. layer 1
    gemm_fused<<<(Nn + 63) / 64, 128, 0, stream>>>(x, 1, Wt1, as1, ad1, H8, asrc, adst, Nn);
    gat_agg<<<(Nn + 31) / 32, 256, 0, stream>>>(H8, asrc, adst, row_start, srcs, b1, hB, Nn, 1);
    // 4. layer 2
    gemm_fused<<<(Nn + 63) / 64, 128, 0, stream>>>(hB, 0, Wt2, as2, ad2, H8, asrc, adst, Nn);
    gat_agg<<<(Nn + 31) / 32, 256, 0, stream>>>(H8, asrc, adst, row_start, srcs, b2, hB, Nn, 0);
    // 5. pool + head
    pool_k<<<GG * PPARTS, 256, 0, stream>>>((const unsigned*)hB, node_end, partial);
    head_k<<<GG, 64, 0, stream>>>(partial, node_end, fcW, fcb, out);
}

// Round 15
// 262.484 us; speedup vs baseline: 1.0274x; 1.0274x over previous
//
#include <hip/hip_runtime.h>
#include <math.h>

#define HC 128
#define GG 64
#define NEG 0.2f
#define TILE 8192
#define BW 128          // nodes per bucket
#define SLOT 8192       // staging slots per bucket (max bucket load ~4600)
#define NBMAX 512
#define LDA 136         // As LDS stride in bf16 elems
#define PPARTS 8        // pool partial slots per graph

typedef __attribute__((ext_vector_type(8))) short short8;
typedef __attribute__((ext_vector_type(4))) float floatx4;
typedef __attribute__((ext_vector_type(2))) float floatx2;

static __device__ __forceinline__ float leaky(float x) { return x > 0.f ? x : NEG * x; }

static __device__ __forceinline__ unsigned short f2bf(float f) {
    unsigned u = __float_as_uint(f);
    u += 0x7FFF + ((u >> 16) & 1);          // round-nearest-even
    return (unsigned short)(u >> 16);
}
static __device__ __forceinline__ float bf2f(unsigned short s) {
    return __uint_as_float(((unsigned)s) << 16);
}

// ---- fp8 e4m3 (OCP) helpers ----
#if __has_builtin(__builtin_amdgcn_cvt_pk_f32_fp8) && __has_builtin(__builtin_amdgcn_cvt_pk_fp8_f32)
template <bool HI>
static __device__ __forceinline__ floatx2 fp8pair(unsigned int w) {
    return __builtin_amdgcn_cvt_pk_f32_fp8((int)w, HI);
}
static __device__ __forceinline__ unsigned int f32x2_fp8(float a, float b) {
    return ((unsigned int)__builtin_amdgcn_cvt_pk_fp8_f32(a, b, 0, false)) & 0xFFFFu;
}
#else
static __device__ __forceinline__ float fp8one(unsigned v) {
    unsigned e = (v >> 3) & 15u, m = v & 7u;
    float mag = e ? __uint_as_float(((e + 120u) << 23) | (m << 20))
                  : (float)m * 0.001953125f;
    return (v & 0x80u) ? -mag : mag;
}
template <bool HI>
static __device__ __forceinline__ floatx2 fp8pair(unsigned int w) {
    unsigned h = HI ? (w >> 16) : w;
    floatx2 r; r.x = fp8one(h & 0xFFu); r.y = fp8one((h >> 8) & 0xFFu);
    return r;
}
static __device__ __forceinline__ unsigned fp8enc(float f) {
    unsigned u = __float_as_uint(f);
    unsigned s = (u >> 24) & 0x80u;
    float a = fabsf(f);
    if (a >= 448.f) return s | 0x7Eu;
    if (a < 0.015625f) {
        unsigned m = (unsigned)(int)rintf(a * 512.f);
        return s | m;
    }
    u = __float_as_uint(a);
    u += 0xFFFFFu + ((u >> 20) & 1u);
    unsigned e8 = (u >> 23) - 120u;
    if (e8 >= 16u) return s | 0x7Eu;
    return s | (e8 << 3) | ((u >> 20) & 7u);
}
static __device__ __forceinline__ unsigned int f32x2_fp8(float a, float b) {
    return fp8enc(a) | (fp8enc(b) << 8);
}
#endif

// accumulate one fp8 row (16 ch) weighted by w into acc[8] (floatx2)
static __device__ __forceinline__ void acc16(floatx2* acc, float w, const uint4& d) {
    floatx2 w2 = {w, w};
    acc[0] += w2 * fp8pair<false>(d.x);
    acc[1] += w2 * fp8pair<true>(d.x);
    acc[2] += w2 * fp8pair<false>(d.y);
    acc[3] += w2 * fp8pair<true>(d.y);
    acc[4] += w2 * fp8pair<false>(d.z);
    acc[5] += w2 * fp8pair<true>(d.z);
    acc[6] += w2 * fp8pair<false>(d.w);
    acc[7] += w2 * fp8pair<true>(d.w);
}

// ---------------- setup: gbcur bases + prep_w + bounds + row_start[Nn] ----------------
__global__ __launch_bounds__(256) void setup_k(const float* __restrict__ W1,
                                               const float* __restrict__ W2,
                                               unsigned short* __restrict__ Wt1,
                                               unsigned short* __restrict__ Wt2,
                                               int* __restrict__ gbcur,
                                               const int* __restrict__ batch,
                                               int* __restrict__ node_end,
                                               int* __restrict__ row_start,
                                               int NB, int Nn, int M) {
    int i = blockIdx.x * 256 + threadIdx.x;
    if (i < NB) gbcur[i] = i * SLOT;
    if (i == 0) row_start[Nn] = M;
    if (i < 32768) {
        // W (fp32 [k][n]) -> bf16 in MFMA A-fragment order
        const float* W = (i >> 14) ? W2 : W1;
        unsigned short* Wt = (i >> 14) ? Wt2 : Wt1;
        int d = i & 16383;
        int j = d & 7;
        int m = (d >> 3) & 15;
        int qf = d >> 7;
        int q = qf & 3;
        int f = qf >> 2;
        int kb = f & 3;
        int ct = f >> 2;
        int n = ct * 16 + m;
        int k = kb * 32 + q * 8 + j;
        Wt[d] = f2bf(W[k * 128 + n]);
    }
    if (i < Nn) {
        int b = batch[i];
        if (i == 0) {
            for (int g = 0; g < b; g++) node_end[g] = 0;
        }
        int bn = (i + 1 < Nn) ? batch[i + 1] : GG;
        for (int g = b; g < bn; g++) node_end[g] = i + 1;
    }
}

// ---------------- phase 1: LDS-binned scatter into fixed bucket slots ----------------
__global__ __launch_bounds__(256) void binscat_k(const int* __restrict__ ei,
                                                 int* __restrict__ gbcur,
                                                 unsigned int* __restrict__ staging,
                                                 int E, int M, int NB) {
    __shared__ unsigned int reorder[TILE];
    __shared__ int s_cnt[NBMAX], s_off[NBMAX], s_run[NBMAX];
    __shared__ int s_wsum[8];
    __shared__ int s_carry;
    const int tid = threadIdx.x;
    const int lane = tid & 63, wid = tid >> 6;
    const int tbase = blockIdx.x * TILE;
    const int tcnt = min(TILE, M - tbase);

    for (int i = tid; i < NB; i += 256) s_cnt[i] = 0;
    if (tid == 0) s_carry = 0;
    __syncthreads();

    for (int t = tid; t < tcnt; t += 256) {
        int i = tbase + t;
        int dst = (i < E) ? ei[E + i] : (i - E);
        atomicAdd(&s_cnt[dst >> 7], 1);
    }
    __syncthreads();

    // exclusive scan s_cnt -> s_off
    for (int base = 0; base < NB; base += 256) {
        int i = base + tid;
        int v = (i < NB) ? s_cnt[i] : 0;
        int incl = v;
        #pragma unroll
        for (int off = 1; off < 64; off <<= 1) {
            int u = __shfl_up(incl, off);
            if (lane >= off) incl += u;
        }
        if (lane == 63) s_wsum[wid] = incl;
        __syncthreads();
        if (tid == 0) {
            int a = 0;
            for (int w = 0; w < 4; w++) { int tv = s_wsum[w]; s_wsum[w] = a; a += tv; }
            s_wsum[4] = a;
        }
        __syncthreads();
        int excl = s_carry + s_wsum[wid] + incl - v;
        if (i < NB) s_off[i] = excl;
        __syncthreads();
        if (tid == 0) s_carry += s_wsum[4];
        __syncthreads();
    }

    for (int b = tid; b < NB; b += 256)
        s_run[b] = atomicAdd(&gbcur[b], s_cnt[b]);
    for (int b = tid; b < NB; b += 256) s_cnt[b] = s_off[b];
    __syncthreads();

    for (int t = tid; t < tcnt; t += 256) {
        int i = tbase + t;
        int src, dst;
        if (i < E) { src = ei[i]; dst = ei[E + i]; }
        else       { src = dst = i - E; }
        unsigned int p = ((unsigned int)dst << 16) | (unsigned int)src;
        int r = atomicAdd(&s_cnt[dst >> 7], 1);
        reorder[r] = p;
    }
    __syncthreads();

    for (int t = tid; t < tcnt; t += 256) {
        unsigned int p = reorder[t];
        int b = p >> 23;                        // dst >> 7
        staging[s_run[b] + (t - s_off[b])] = p;
    }
}

// ---------------- phase 2: bucket-base reduce + local scan -> row_start + srcs --------
__global__ __launch_bounds__(256) void unbin_k(const unsigned int* __restrict__ staging,
                                               const int* __restrict__ gbcur,
                                               int* __restrict__ row_start,
                                               unsigned short* __restrict__ srcs, int Nn) {
    __shared__ int s_cnt[BW];
    __shared__ int s_cur[BW];
    __shared__ int s_w[4];
    int b = blockIdx.x, t = threadIdx.x;
    int sbase = b * SLOT;
    int cnt = gbcur[b] - sbase;

    // bucket base = sum of counts of buckets < b
    int pacc = 0;
    for (int i = t; i < b; i += 256) pacc += gbcur[i] - i * SLOT;
    #pragma unroll
    for (int off = 1; off < 64; off <<= 1) pacc += __shfl_xor(pacc, off);
    if ((t & 63) == 0) s_w[t >> 6] = pacc;
    __syncthreads();
    int bb = s_w[0] + s_w[1] + s_w[2] + s_w[3];
    __syncthreads();

    int n0 = b * BW;
    if (t < BW) s_cnt[t] = 0;
    __syncthreads();
    for (int j = t; j < cnt; j += 256)
        atomicAdd(&s_cnt[(staging[sbase + j] >> 16) & (BW - 1)], 1);
    __syncthreads();
    int v = (t < BW) ? s_cnt[t] : 0;
    int incl = v;
    #pragma unroll
    for (int off = 1; off < 64; off <<= 1) {
        int u = __shfl_up(incl, off);
        if ((t & 63) >= off) incl += u;
    }
    if (t < BW && (t & 63) == 63) s_w[t >> 6] = incl;
    __syncthreads();
    int excl = incl - v + ((t >= 64 && t < BW) ? s_w[0] : 0);
    if (t < BW) {
        s_cur[t] = bb + excl;
        if (n0 + t < Nn) row_start[n0 + t] = bb + excl;
    }
    __syncthreads();
    for (int j = t; j < cnt; j += 256) {
        unsigned int p = staging[sbase + j];
        int ln = (int)(p >> 16) & (BW - 1);
        int r = atomicAdd(&s_cur[ln], 1);
        srcs[r] = (unsigned short)(p & 0xFFFFu);
    }
}

// ---------------- fused MFMA GEMM + attention dots + fp8 quantize ----------------
// W fragments are read straight from Wt (32KB, L2-resident, fragment order) —
// no LDS staging for W: LDS 50K->17.4K, ~9 blocks/CU, all 782 blocks co-resident.
__global__ __launch_bounds__(128) void gemm_fused(const void* __restrict__ Xv,
                                                  int x_f32,
                                                  const unsigned short* __restrict__ Wt,
                                                  const float* __restrict__ att_s,
                                                  const float* __restrict__ att_d,
                                                  unsigned char* __restrict__ H8,
                                                  float* __restrict__ a_src,
                                                  float* __restrict__ a_dst,
                                                  int n_rows) {
    __shared__ unsigned short As[64 * LDA];   // 17408 B
    const int tid = threadIdx.x;
    const int row0 = blockIdx.x * 64;

    if (x_f32) {
        const float* X = (const float*)Xv;
        for (int i = tid; i < 2048; i += 128) {
            int r = i >> 5;
            int c4 = (i & 31) << 2;
            int gr = row0 + r;
            float4 v = (gr < n_rows) ? ((const float4*)&X[(size_t)gr * 128])[i & 31]
                                     : make_float4(0.f, 0.f, 0.f, 0.f);
            ushort4 bv = {f2bf(v.x), f2bf(v.y), f2bf(v.z), f2bf(v.w)};
            *(ushort4*)&As[r * LDA + c4] = bv;
        }
    } else {
        const unsigned short* X = (const unsigned short*)Xv;
        for (int i = tid; i < 1024; i += 128) {
            int r = i >> 4;
            int c8 = (i & 15) << 3;
            int gr = row0 + r;
            uint4 v = (gr < n_rows) ? *(const uint4*)&X[(size_t)gr * 128 + c8]
                                    : make_uint4(0, 0, 0, 0);
            *(uint4*)&As[r * LDA + c8] = v;
        }
    }
    __syncthreads();

    const int lane = tid & 63;
    const int wave = tid >> 6;
    const int m = lane & 15;          // node-in-tile (C col)
    const int quad = lane >> 4;       // channel quad (C row group)
    const int wr0 = wave * 32;

    floatx4 acc[2][8];
    #pragma unroll
    for (int nt = 0; nt < 2; nt++)
        #pragma unroll
        for (int ct = 0; ct < 8; ct++)
            acc[nt][ct] = (floatx4){0.f, 0.f, 0.f, 0.f};

    #pragma unroll
    for (int kb = 0; kb < 4; kb++) {
        short8 x0 = *(const short8*)&As[(wr0 + m) * LDA + kb * 32 + quad * 8];
        short8 x1 = *(const short8*)&As[(wr0 + 16 + m) * LDA + kb * 32 + quad * 8];
        #pragma unroll
        for (int ct = 0; ct < 8; ct++) {
            // fragment order: offset = ((ct*4+kb)*4 + quad)*128 + m*8 (coalesced 1KB/chunk)
            short8 wf = *(const short8*)&Wt[(((ct * 4 + kb) * 4) + quad) * 128 + m * 8];
            acc[0][ct] = __builtin_amdgcn_mfma_f32_16x16x32_bf16(wf, x0, acc[0][ct], 0, 0, 0);
            acc[1][ct] = __builtin_amdgcn_mfma_f32_16x16x32_bf16(wf, x1, acc[1][ct], 0, 0, 0);
        }
    }

    const int q4 = quad * 4;
    #pragma unroll
    for (int nt = 0; nt < 2; nt++) {
        int node = row0 + wr0 + nt * 16 + m;
        bool vld = node < n_rows;
        float ps[4] = {0.f, 0.f, 0.f, 0.f};
        float pd[4] = {0.f, 0.f, 0.f, 0.f};
        #pragma unroll
        for (int ct = 0; ct < 8; ct++) {
            floatx4 v = acc[nt][ct];
            int c0 = ct * 16 + q4;
            float4 avs = *(const float4*)&att_s[c0];
            float4 avd = *(const float4*)&att_d[c0];
            int h = ct >> 1;
            ps[h] += v[0] * avs.x + v[1] * avs.y + v[2] * avs.z + v[3] * avs.w;
            pd[h] += v[0] * avd.x + v[1] * avd.y + v[2] * avd.z + v[3] * avd.w;
            if (vld) {
                unsigned pk01 = f32x2_fp8(v[0], v[1]);
                unsigned pk23 = f32x2_fp8(v[2], v[3]);
                *(unsigned*)&H8[(size_t)node * 128 + c0] = pk01 | (pk23 << 16);
            }
        }
        #pragma unroll
        for (int h = 0; h < 4; h++) {
            ps[h] += __shfl_xor(ps[h], 16); ps[h] += __shfl_xor(ps[h], 32);
            pd[h] += __shfl_xor(pd[h], 16); pd[h] += __shfl_xor(pd[h], 32);
        }
        if (lane < 16 && vld) {
            float4 s4 = {ps[0], ps[1], ps[2], ps[3]};
            float4 d4 = {pd[0], pd[1], pd[2], pd[3]};
            *(float4*)&a_src[node * 4] = s4;
            *(float4*)&a_dst[node * 4] = d4;
        }
    }
}

// ---------------- GAT aggregation: 8 lanes/node, fp8 gather, uint2 srcs x4 ----------
__global__ __launch_bounds__(256) void gat_agg(const unsigned char* __restrict__ H8,
                                               const float* __restrict__ a_src,
                                               const float* __restrict__ a_dst,
                                               const int* __restrict__ row_start,
                                               const unsigned short* __restrict__ srcs,
                                               const float* __restrict__ bias,
                                               unsigned short* __restrict__ OUT,
                                               int n_rows, int elu) {
    int n = (blockIdx.x * 256 + threadIdx.x) >> 3;
    if (n >= n_rows) return;
    int li = threadIdx.x & 7;
    int hd = li >> 1;
    int base = row_start[n];
    int end = row_start[n + 1];
    float adh = a_dst[n * 4 + hd];

    floatx2 acc[8];
    #pragma unroll
    for (int k = 0; k < 8; k++) acc[k] = (floatx2){0.f, 0.f};
    float wsum = 0.f;

    int j = base;
    // alignment prologue: advance j to a multiple of 4 (srcs 256B-aligned)
    int head_n = min(end - j, (4 - (base & 3)) & 3);
    for (int q = 0; q < head_n; q++, j++) {
        int s0 = srcs[j];
        float w0 = __expf(leaky(a_src[s0 * 4 + hd] + adh));
        uint4 d0 = *(const uint4*)&H8[(size_t)s0 * 128 + li * 16];
        acc16(acc, w0, d0);
        wsum += w0;
    }
    // main: 4 edges per iter, single 8B srcs load
    for (; j + 4 <= end; j += 4) {
        uint2 sv = *(const uint2*)&srcs[j];
        int s0 = sv.x & 0xFFFFu, s1 = sv.x >> 16;
        int s2 = sv.y & 0xFFFFu, s3 = sv.y >> 16;
        float a0 = a_src[s0 * 4 + hd];
        float a1 = a_src[s1 * 4 + hd];
        float a2 = a_src[s2 * 4 + hd];
        float a3 = a_src[s3 * 4 + hd];
        uint4 d0 = *(const uint4*)&H8[(size_t)s0 * 128 + li * 16];
        uint4 d1 = *(const uint4*)&H8[(size_t)s1 * 128 + li * 16];
        uint4 d2 = *(const uint4*)&H8[(size_t)s2 * 128 + li * 16];
        uint4 d3 = *(const uint4*)&H8[(size_t)s3 * 128 + li * 16];
        float w0 = __expf(leaky(a0 + adh));
        float w1 = __expf(leaky(a1 + adh));
        float w2 = __expf(leaky(a2 + adh));
        float w3 = __expf(leaky(a3 + adh));
        acc16(acc, w0, d0);
        acc16(acc, w1, d1);
        acc16(acc, w2, d2);
        acc16(acc, w3, d3);
        wsum += (w0 + w1) + (w2 + w3);
    }
    // tail
    for (; j < end; j++) {
        int s0 = srcs[j];
        float w0 = __expf(leaky(a_src[s0 * 4 + hd] + adh));
        uint4 d0 = *(const uint4*)&H8[(size_t)s0 * 128 + li * 16];
        acc16(acc, w0, d0);
        wsum += w0;
    }

    float ih = 1.0f / (wsum + 1e-16f);
    float o[16];
    #pragma unroll
    for (int k = 0; k < 8; k++) {
        float2 bv = *(const float2*)&bias[li * 16 + 2 * k];
        o[2 * k]     = acc[k].x * ih + bv.x;
        o[2 * k + 1] = acc[k].y * ih + bv.y;
    }
    if (elu) {
        #pragma unroll
        for (int k = 0; k < 16; k++) o[k] = o[k] > 0.f ? o[k] : __expf(o[k]) - 1.f;
    }
    unsigned int pk[8];
    #pragma unroll
    for (int k = 0; k < 8; k++)
        pk[k] = ((unsigned)f2bf(o[2 * k + 1]) << 16) | (unsigned)f2bf(o[2 * k]);
    uint4 s0v = {pk[0], pk[1], pk[2], pk[3]};
    uint4 s1v = {pk[4], pk[5], pk[6], pk[7]};
    unsigned short* op = &OUT[(size_t)n * 128 + li * 16];
    *(uint4*)op = s0v;
    *(uint4*)(op + 8) = s1v;
}

// ---------------- mean pool: atomic-free partial sums ----------------
__global__ __launch_bounds__(256) void pool_k(const unsigned* __restrict__ H2u,
                                              const int* __restrict__ node_end,
                                              float* __restrict__ partial) {
    __shared__ float ls[4][128];
    int g = blockIdx.x >> 3;
    int p = blockIdx.x & (PPARTS - 1);
    int s = (g > 0) ? node_end[g - 1] : 0;
    int e = node_end[g];
    int cnt = e - s;
    int chunk = (cnt + PPARTS - 1) >> 3;
    int n0 = s + p * chunk;
    int n1 = min(n0 + chunk, e);
    int col = threadIdx.x & 63;
    int nr = threadIdx.x >> 6;
    float ax = 0.f, ay = 0.f;
    for (int n = n0 + nr; n < n1; n += 4) {
        unsigned u = H2u[(size_t)n * 64 + col];
        ax += bf2f((unsigned short)(u & 0xFFFFu));
        ay += bf2f((unsigned short)(u >> 16));
    }
    ls[nr][col * 2] = ax;
    ls[nr][col * 2 + 1] = ay;
    __syncthreads();
    if (threadIdx.x < 128) {
        float v = ls[0][threadIdx.x] + ls[1][threadIdx.x] +
                  ls[2][threadIdx.x] + ls[3][threadIdx.x];
        partial[(size_t)(p * GG + g) * 128 + threadIdx.x] = v;
    }
}

// ---------------- final: sum partials, mean, fc + log_softmax ----------------
__global__ __launch_bounds__(64) void head_k(const float* __restrict__ partial,
                                             const int* __restrict__ node_end,
                                             const float* __restrict__ fcW,
                                             const float* __restrict__ fcb,
                                             float* __restrict__ out) {
    __shared__ float p[128];
    __shared__ float lg[8];
    int g = blockIdx.x, t = threadIdx.x;
    int c = node_end[g] - (g > 0 ? node_end[g - 1] : 0);
    float cnt = fmaxf((float)c, 1.0f);
    float v0 = 0.f, v1 = 0.f;
    #pragma unroll
    for (int q = 0; q < PPARTS; q++) {
        v0 += partial[(size_t)(q * GG + g) * 128 + t];
        v1 += partial[(size_t)(q * GG + g) * 128 + 64 + t];
    }
    p[t] = v0 / cnt;
    p[t + 64] = v1 / cnt;
    __syncthreads();
    if (t < 8) {
        float s = fcb[t];
        for (int k = 0; k < 128; k++) s += p[k] * fcW[k * 8 + t];
        lg[t] = s;
    }
    __syncthreads();
    if (t == 0) {
        float m = lg[0];
        for (int j = 1; j < 8; j++) m = fmaxf(m, lg[j]);
        float se = 0.f;
        for (int j = 0; j < 8; j++) se += expf(lg[j] - m);
        float lse = logf(se) + m;
        for (int j = 0; j < 8; j++) out[g * 8 + j] = lg[j] - lse;
    }
}

extern "C" void kernel_launch(void* const* d_in, const int* in_sizes, int n_in,
                              void* d_out, int out_size, void* d_ws, size_t ws_size,
                              hipStream_t stream) {
    const float* x    = (const float*)d_in[0];
    const int*   ei   = (const int*)d_in[1];
    const int*   batch= (const int*)d_in[2];
    const float* W1   = (const float*)d_in[3];
    const float* as1  = (const float*)d_in[4];
    const float* ad1  = (const float*)d_in[5];
    const float* b1   = (const float*)d_in[6];
    const float* W2   = (const float*)d_in[7];
    const float* as2  = (const float*)d_in[8];
    const float* ad2  = (const float*)d_in[9];
    const float* b2   = (const float*)d_in[10];
    const float* fcW  = (const float*)d_in[11];
    const float* fcb  = (const float*)d_in[12];
    float* out = (float*)d_out;

    const int Nn = in_sizes[0] / HC;       // 50000
    const int E  = in_sizes[1] / 2;        // 1600000
    const int M  = E + Nn;                 // edges incl. self loops
    const int NB = (Nn + BW - 1) / BW;     // 391 buckets

    char* ws = (char*)d_ws;
    size_t off = 0;
    auto alloc = [&](size_t bytes) -> char* {
        char* p = ws + off;
        off = (off + bytes + 255) & ~(size_t)255;
        return p;
    };
    size_t hB_bytes  = (size_t)Nn * HC * 2;     // bf16 node features
    size_t stg_bytes = (size_t)NB * SLOT * 4;   // CSR staging
    char* hB_region = alloc(hB_bytes > stg_bytes ? hB_bytes : stg_bytes);
    unsigned short* hB      = (unsigned short*)hB_region;     // bf16 agg out / gemm in
    unsigned int*   staging = (unsigned int*)hB_region;       // aliased: used before hB
    unsigned char*  H8      = (unsigned char*)alloc((size_t)Nn * HC);  // fp8 h
    float* asrc      = (float*)alloc((size_t)Nn * 4 * 4);
    float* adst      = (float*)alloc((size_t)Nn * 4 * 4);
    unsigned short* srcs = (unsigned short*)alloc((size_t)M * 2);
    int*   row_start = (int*)alloc((size_t)(Nn + 1) * 4);
    float* partial   = (float*)alloc((size_t)PPARTS * GG * HC * 4);
    int*   node_end  = (int*)alloc((size_t)GG * 4);
    int*   gbcur     = (int*)alloc((size_t)NB * 4);
    unsigned short* Wt1 = (unsigned short*)alloc(16384 * 2);
    unsigned short* Wt2 = (unsigned short*)alloc(16384 * 2);

    // 1. setup (gbcur bases + prep_w + bounds + row_start[Nn])
    setup_k<<<(Nn + 255) / 256, 256, 0, stream>>>(W1, W2, Wt1, Wt2, gbcur, batch,
                                                  node_end, row_start, NB, Nn, M);
    // 2. CSR build
    binscat_k<<<(M + TILE - 1) / TILE, 256, 0, stream>>>(ei, gbcur, staging, E, M, NB);
    unbin_k<<<NB, 256, 0, stream>>>(staging, gbcur, row_start, srcs, Nn);
    // 3. layer 1
    gemm_fused<<<(Nn + 63) / 64, 128, 0, stream>>>(x, 1, Wt1, as1, ad1, H8, asrc, adst, Nn);
    gat_agg<<<(Nn + 31) / 32, 256, 0, stream>>>(H8, asrc, adst, row_start, srcs, b1, hB, Nn, 1);
    // 4. layer 2
    gemm_fused<<<(Nn + 63) / 64, 128, 0, stream>>>(hB, 0, Wt2, as2, ad2, H8, asrc, adst, Nn);
    gat_agg<<<(Nn + 31) / 32, 256, 0, stream>>>(H8, asrc, adst, row_start, srcs, b2, hB, Nn, 0);
    // 5. pool + head
    pool_k<<<GG * PPARTS, 256, 0, stream>>>((const unsigned*)hB, node_end, partial);
    head_k<<<GG, 64, 0, stream>>>(partial, node_end, fcW, fcb, out);
}

// Round 16
// 244.834 us; speedup vs baseline: 1.1015x; 1.0721x over previous
//
#include <hip/hip_runtime.h>
#include <math.h>

#define HC 128
#define GG 64
#define NEG 0.2f
#define TILE 8192
#define BW 128          // nodes per bucket
#define SLOT 8192       // staging slots per bucket (max bucket load ~4600)
#define NBMAX 512
#define LDA 136         // As LDS stride in bf16 elems

typedef __attribute__((ext_vector_type(8))) short short8;
typedef __attribute__((ext_vector_type(4))) float floatx4;
typedef __attribute__((ext_vector_type(2))) float floatx2;

static __device__ __forceinline__ float leaky(float x) { return x > 0.f ? x : NEG * x; }

static __device__ __forceinline__ unsigned short f2bf(float f) {
    unsigned u = __float_as_uint(f);
    u += 0x7FFF + ((u >> 16) & 1);          // round-nearest-even
    return (unsigned short)(u >> 16);
}
static __device__ __forceinline__ float bf2f(unsigned short s) {
    return __uint_as_float(((unsigned)s) << 16);
}

// ---- fp8 e4m3 (OCP) helpers ----
#if __has_builtin(__builtin_amdgcn_cvt_pk_f32_fp8) && __has_builtin(__builtin_amdgcn_cvt_pk_fp8_f32)
template <bool HI>
static __device__ __forceinline__ floatx2 fp8pair(unsigned int w) {
    return __builtin_amdgcn_cvt_pk_f32_fp8((int)w, HI);
}
static __device__ __forceinline__ unsigned int f32x2_fp8(float a, float b) {
    return ((unsigned int)__builtin_amdgcn_cvt_pk_fp8_f32(a, b, 0, false)) & 0xFFFFu;
}
#else
static __device__ __forceinline__ float fp8one(unsigned v) {
    unsigned e = (v >> 3) & 15u, m = v & 7u;
    float mag = e ? __uint_as_float(((e + 120u) << 23) | (m << 20))
                  : (float)m * 0.001953125f;
    return (v & 0x80u) ? -mag : mag;
}
template <bool HI>
static __device__ __forceinline__ floatx2 fp8pair(unsigned int w) {
    unsigned h = HI ? (w >> 16) : w;
    floatx2 r; r.x = fp8one(h & 0xFFu); r.y = fp8one((h >> 8) & 0xFFu);
    return r;
}
static __device__ __forceinline__ unsigned fp8enc(float f) {
    unsigned u = __float_as_uint(f);
    unsigned s = (u >> 24) & 0x80u;
    float a = fabsf(f);
    if (a >= 448.f) return s | 0x7Eu;
    if (a < 0.015625f) {
        unsigned m = (unsigned)(int)rintf(a * 512.f);
        return s | m;
    }
    u = __float_as_uint(a);
    u += 0xFFFFFu + ((u >> 20) & 1u);
    unsigned e8 = (u >> 23) - 120u;
    if (e8 >= 16u) return s | 0x7Eu;
    return s | (e8 << 3) | ((u >> 20) & 7u);
}
static __device__ __forceinline__ unsigned int f32x2_fp8(float a, float b) {
    return fp8enc(a) | (fp8enc(b) << 8);
}
#endif

// accumulate one fp8 row (16 ch) weighted by w into acc[8] (floatx2)
static __device__ __forceinline__ void acc16(floatx2* acc, float w, const uint4& d) {
    floatx2 w2 = {w, w};
    acc[0] += w2 * fp8pair<false>(d.x);
    acc[1] += w2 * fp8pair<true>(d.x);
    acc[2] += w2 * fp8pair<false>(d.y);
    acc[3] += w2 * fp8pair<true>(d.y);
    acc[4] += w2 * fp8pair<false>(d.z);
    acc[5] += w2 * fp8pair<true>(d.z);
    acc[6] += w2 * fp8pair<false>(d.w);
    acc[7] += w2 * fp8pair<true>(d.w);
}

// ---------------- setup: gbcur bases + prep_w + bounds + row_start[Nn] ----------------
__global__ __launch_bounds__(256) void setup_k(const float* __restrict__ W1,
                                               const float* __restrict__ W2,
                                               unsigned short* __restrict__ Wt1,
                                               unsigned short* __restrict__ Wt2,
                                               int* __restrict__ gbcur,
                                               const int* __restrict__ batch,
                                               int* __restrict__ node_end,
                                               int* __restrict__ row_start,
                                               int NB, int Nn, int M) {
    int i = blockIdx.x * 256 + threadIdx.x;
    if (i < NB) gbcur[i] = i * SLOT;
    if (i == 0) row_start[Nn] = M;
    if (i < 32768) {
        // W (fp32 [k][n]) -> bf16 in MFMA A-fragment order
        const float* W = (i >> 14) ? W2 : W1;
        unsigned short* Wt = (i >> 14) ? Wt2 : Wt1;
        int d = i & 16383;
        int j = d & 7;
        int m = (d >> 3) & 15;
        int qf = d >> 7;
        int q = qf & 3;
        int f = qf >> 2;
        int kb = f & 3;
        int ct = f >> 2;
        int n = ct * 16 + m;
        int k = kb * 32 + q * 8 + j;
        Wt[d] = f2bf(W[k * 128 + n]);
    }
    if (i < Nn) {
        int b = batch[i];
        if (i == 0) {
            for (int g = 0; g < b; g++) node_end[g] = 0;
        }
        int bn = (i + 1 < Nn) ? batch[i + 1] : GG;
        for (int g = b; g < bn; g++) node_end[g] = i + 1;
    }
}

// ---------------- fused: binscat (blocks [0,NBIN)) ∥ gemm layer-1 (rest) ----------
// Shared LDS union: binscat needs 38.9KB; gemm needs 17.4KB.
__global__ __launch_bounds__(256) void fused_k(const int* __restrict__ ei,
                                               int* __restrict__ gbcur,
                                               unsigned int* __restrict__ staging,
                                               int E, int M, int NB, int NBIN,
                                               const float* __restrict__ X,
                                               const unsigned short* __restrict__ Wt,
                                               const float* __restrict__ att_s,
                                               const float* __restrict__ att_d,
                                               unsigned char* __restrict__ H8,
                                               float* __restrict__ a_src,
                                               float* __restrict__ a_dst,
                                               int n_rows) {
    __shared__ __align__(16) char smem[39040];
    const int tid = threadIdx.x;

    if ((int)blockIdx.x < NBIN) {
        // ---------------- binscat ----------------
        unsigned int* reorder = (unsigned int*)smem;           // 32768 B
        int* s_cnt  = (int*)(smem + 32768);                    // 2048
        int* s_off  = (int*)(smem + 34816);                    // 2048
        int* s_run  = (int*)(smem + 36864);                    // 2048
        int* s_wsum = (int*)(smem + 38912);                    // 32
        int* s_carry= (int*)(smem + 38944);
        const int lane = tid & 63, wid = tid >> 6;
        const int tbase = blockIdx.x * TILE;
        const int tcnt = min(TILE, M - tbase);

        for (int i = tid; i < NB; i += 256) s_cnt[i] = 0;
        if (tid == 0) *s_carry = 0;
        __syncthreads();

        for (int t = tid; t < tcnt; t += 256) {
            int i = tbase + t;
            int dst = (i < E) ? ei[E + i] : (i - E);
            atomicAdd(&s_cnt[dst >> 7], 1);
        }
        __syncthreads();

        // exclusive scan s_cnt -> s_off
        for (int base = 0; base < NB; base += 256) {
            int i = base + tid;
            int v = (i < NB) ? s_cnt[i] : 0;
            int incl = v;
            #pragma unroll
            for (int off = 1; off < 64; off <<= 1) {
                int u = __shfl_up(incl, off);
                if (lane >= off) incl += u;
            }
            if (lane == 63) s_wsum[wid] = incl;
            __syncthreads();
            if (tid == 0) {
                int a = 0;
                for (int w = 0; w < 4; w++) { int tv = s_wsum[w]; s_wsum[w] = a; a += tv; }
                s_wsum[4] = a;
            }
            __syncthreads();
            int excl = *s_carry + s_wsum[wid] + incl - v;
            if (i < NB) s_off[i] = excl;
            __syncthreads();
            if (tid == 0) *s_carry += s_wsum[4];
            __syncthreads();
        }

        for (int b = tid; b < NB; b += 256)
            s_run[b] = atomicAdd(&gbcur[b], s_cnt[b]);
        for (int b = tid; b < NB; b += 256) s_cnt[b] = s_off[b];
        __syncthreads();

        for (int t = tid; t < tcnt; t += 256) {
            int i = tbase + t;
            int src, dst;
            if (i < E) { src = ei[i]; dst = ei[E + i]; }
            else       { src = dst = i - E; }
            unsigned int p = ((unsigned int)dst << 16) | (unsigned int)src;
            int r = atomicAdd(&s_cnt[dst >> 7], 1);
            reorder[r] = p;
        }
        __syncthreads();

        for (int t = tid; t < tcnt; t += 256) {
            unsigned int p = reorder[t];
            int b = p >> 23;                        // dst >> 7
            staging[s_run[b] + (t - s_off[b])] = p;
        }
    } else {
        // ---------------- gemm layer-1 (fp32 X input), 4 waves x 16 rows ----------------
        unsigned short* As = (unsigned short*)smem;   // 64*LDA*2 = 17408 B
        const int gb = blockIdx.x - NBIN;
        const int row0 = gb * 64;

        for (int i = tid; i < 2048; i += 256) {
            int r = i >> 5;
            int c4 = (i & 31) << 2;
            int gr = row0 + r;
            float4 v = (gr < n_rows) ? ((const float4*)&X[(size_t)gr * 128])[i & 31]
                                     : make_float4(0.f, 0.f, 0.f, 0.f);
            ushort4 bv = {f2bf(v.x), f2bf(v.y), f2bf(v.z), f2bf(v.w)};
            *(ushort4*)&As[r * LDA + c4] = bv;
        }
        __syncthreads();

        const int lane = tid & 63;
        const int wave = tid >> 6;
        const int m = lane & 15;
        const int quad = lane >> 4;
        const int wr = wave * 16;

        floatx4 acc[8];
        #pragma unroll
        for (int ct = 0; ct < 8; ct++) acc[ct] = (floatx4){0.f, 0.f, 0.f, 0.f};

        #pragma unroll
        for (int kb = 0; kb < 4; kb++) {
            short8 x0 = *(const short8*)&As[(wr + m) * LDA + kb * 32 + quad * 8];
            #pragma unroll
            for (int ct = 0; ct < 8; ct++) {
                short8 wf = *(const short8*)&Wt[(((ct * 4 + kb) * 4) + quad) * 128 + m * 8];
                acc[ct] = __builtin_amdgcn_mfma_f32_16x16x32_bf16(wf, x0, acc[ct], 0, 0, 0);
            }
        }

        const int q4 = quad * 4;
        int node = row0 + wr + m;
        bool vld = node < n_rows;
        float ps[4] = {0.f, 0.f, 0.f, 0.f};
        float pd[4] = {0.f, 0.f, 0.f, 0.f};
        #pragma unroll
        for (int ct = 0; ct < 8; ct++) {
            floatx4 v = acc[ct];
            int c0 = ct * 16 + q4;
            float4 avs = *(const float4*)&att_s[c0];
            float4 avd = *(const float4*)&att_d[c0];
            int h = ct >> 1;
            ps[h] += v[0] * avs.x + v[1] * avs.y + v[2] * avs.z + v[3] * avs.w;
            pd[h] += v[0] * avd.x + v[1] * avd.y + v[2] * avd.z + v[3] * avd.w;
            if (vld) {
                unsigned pk01 = f32x2_fp8(v[0], v[1]);
                unsigned pk23 = f32x2_fp8(v[2], v[3]);
                *(unsigned*)&H8[(size_t)node * 128 + c0] = pk01 | (pk23 << 16);
            }
        }
        #pragma unroll
        for (int h = 0; h < 4; h++) {
            ps[h] += __shfl_xor(ps[h], 16); ps[h] += __shfl_xor(ps[h], 32);
            pd[h] += __shfl_xor(pd[h], 16); pd[h] += __shfl_xor(pd[h], 32);
        }
        if (lane < 16 && vld) {
            float4 s4 = {ps[0], ps[1], ps[2], ps[3]};
            float4 d4 = {pd[0], pd[1], pd[2], pd[3]};
            *(float4*)&a_src[node * 4] = s4;
            *(float4*)&a_dst[node * 4] = d4;
        }
    }
}

// ---------------- phase 2: bucket-base reduce + local scan -> row_start + srcs --------
__global__ __launch_bounds__(256) void unbin_k(const unsigned int* __restrict__ staging,
                                               const int* __restrict__ gbcur,
                                               int* __restrict__ row_start,
                                               unsigned short* __restrict__ srcs, int Nn) {
    __shared__ int s_cnt[BW];
    __shared__ int s_cur[BW];
    __shared__ int s_w[4];
    int b = blockIdx.x, t = threadIdx.x;
    int sbase = b * SLOT;
    int cnt = gbcur[b] - sbase;

    // bucket base = sum of counts of buckets < b
    int pacc = 0;
    for (int i = t; i < b; i += 256) pacc += gbcur[i] - i * SLOT;
    #pragma unroll
    for (int off = 1; off < 64; off <<= 1) pacc += __shfl_xor(pacc, off);
    if ((t & 63) == 0) s_w[t >> 6] = pacc;
    __syncthreads();
    int bb = s_w[0] + s_w[1] + s_w[2] + s_w[3];
    __syncthreads();

    int n0 = b * BW;
    if (t < BW) s_cnt[t] = 0;
    __syncthreads();
    for (int j = t; j < cnt; j += 256)
        atomicAdd(&s_cnt[(staging[sbase + j] >> 16) & (BW - 1)], 1);
    __syncthreads();
    int v = (t < BW) ? s_cnt[t] : 0;
    int incl = v;
    #pragma unroll
    for (int off = 1; off < 64; off <<= 1) {
        int u = __shfl_up(incl, off);
        if ((t & 63) >= off) incl += u;
    }
    if (t < BW && (t & 63) == 63) s_w[t >> 6] = incl;
    __syncthreads();
    int excl = incl - v + ((t >= 64 && t < BW) ? s_w[0] : 0);
    if (t < BW) {
        s_cur[t] = bb + excl;
        if (n0 + t < Nn) row_start[n0 + t] = bb + excl;
    }
    __syncthreads();
    for (int j = t; j < cnt; j += 256) {
        unsigned int p = staging[sbase + j];
        int ln = (int)(p >> 16) & (BW - 1);
        int r = atomicAdd(&s_cur[ln], 1);
        srcs[r] = (unsigned short)(p & 0xFFFFu);
    }
}

// ---------------- gemm layer-2 (bf16 input), original 2-wave form ----------------
__global__ __launch_bounds__(128) void gemm_fused(const unsigned short* __restrict__ X,
                                                  const unsigned short* __restrict__ Wt,
                                                  const float* __restrict__ att_s,
                                                  const float* __restrict__ att_d,
                                                  unsigned char* __restrict__ H8,
                                                  float* __restrict__ a_src,
                                                  float* __restrict__ a_dst,
                                                  int n_rows) {
    __shared__ unsigned short As[64 * LDA];   // 17408 B
    const int tid = threadIdx.x;
    const int row0 = blockIdx.x * 64;

    for (int i = tid; i < 1024; i += 128) {
        int r = i >> 4;
        int c8 = (i & 15) << 3;
        int gr = row0 + r;
        uint4 v = (gr < n_rows) ? *(const uint4*)&X[(size_t)gr * 128 + c8]
                                : make_uint4(0, 0, 0, 0);
        *(uint4*)&As[r * LDA + c8] = v;
    }
    __syncthreads();

    const int lane = tid & 63;
    const int wave = tid >> 6;
    const int m = lane & 15;
    const int quad = lane >> 4;
    const int wr0 = wave * 32;

    floatx4 acc[2][8];
    #pragma unroll
    for (int nt = 0; nt < 2; nt++)
        #pragma unroll
        for (int ct = 0; ct < 8; ct++)
            acc[nt][ct] = (floatx4){0.f, 0.f, 0.f, 0.f};

    #pragma unroll
    for (int kb = 0; kb < 4; kb++) {
        short8 x0 = *(const short8*)&As[(wr0 + m) * LDA + kb * 32 + quad * 8];
        short8 x1 = *(const short8*)&As[(wr0 + 16 + m) * LDA + kb * 32 + quad * 8];
        #pragma unroll
        for (int ct = 0; ct < 8; ct++) {
            short8 wf = *(const short8*)&Wt[(((ct * 4 + kb) * 4) + quad) * 128 + m * 8];
            acc[0][ct] = __builtin_amdgcn_mfma_f32_16x16x32_bf16(wf, x0, acc[0][ct], 0, 0, 0);
            acc[1][ct] = __builtin_amdgcn_mfma_f32_16x16x32_bf16(wf, x1, acc[1][ct], 0, 0, 0);
        }
    }

    const int q4 = quad * 4;
    #pragma unroll
    for (int nt = 0; nt < 2; nt++) {
        int node = row0 + wr0 + nt * 16 + m;
        bool vld = node < n_rows;
        float ps[4] = {0.f, 0.f, 0.f, 0.f};
        float pd[4] = {0.f, 0.f, 0.f, 0.f};
        #pragma unroll
        for (int ct = 0; ct < 8; ct++) {
            floatx4 v = acc[nt][ct];
            int c0 = ct * 16 + q4;
            float4 avs = *(const float4*)&att_s[c0];
            float4 avd = *(const float4*)&att_d[c0];
            int h = ct >> 1;
            ps[h] += v[0] * avs.x + v[1] * avs.y + v[2] * avs.z + v[3] * avs.w;
            pd[h] += v[0] * avd.x + v[1] * avd.y + v[2] * avd.z + v[3] * avd.w;
            if (vld) {
                unsigned pk01 = f32x2_fp8(v[0], v[1]);
                unsigned pk23 = f32x2_fp8(v[2], v[3]);
                *(unsigned*)&H8[(size_t)node * 128 + c0] = pk01 | (pk23 << 16);
            }
        }
        #pragma unroll
        for (int h = 0; h < 4; h++) {
            ps[h] += __shfl_xor(ps[h], 16); ps[h] += __shfl_xor(ps[h], 32);
            pd[h] += __shfl_xor(pd[h], 16); pd[h] += __shfl_xor(pd[h], 32);
        }
        if (lane < 16 && vld) {
            float4 s4 = {ps[0], ps[1], ps[2], ps[3]};
            float4 d4 = {pd[0], pd[1], pd[2], pd[3]};
            *(float4*)&a_src[node * 4] = s4;
            *(float4*)&a_dst[node * 4] = d4;
        }
    }
}

// ---------------- GAT aggregation: 8 lanes/node, fp8 gather, uint2 srcs x4 ----------
// mode 0 (layer 1): elu + bf16 store to OUT.
// mode 1 (layer 2): no elu; block-local pool -> partial[block*4 + slot][128]
//                   (slot = graph - batch[block_first_node]; 32-node block spans <=4 graphs).
__global__ __launch_bounds__(256) void gat_agg(const unsigned char* __restrict__ H8,
                                               const float* __restrict__ a_src,
                                               const float* __restrict__ a_dst,
                                               const int* __restrict__ row_start,
                                               const unsigned short* __restrict__ srcs,
                                               const float* __restrict__ bias,
                                               unsigned short* __restrict__ OUT,
                                               const int* __restrict__ batch,
                                               float* __restrict__ partial,
                                               int n_rows, int mode) {
    __shared__ float ls[32][128];
    __shared__ int sg[32];
    int n = (blockIdx.x * 256 + threadIdx.x) >> 3;
    int li = threadIdx.x & 7;
    int hd = li >> 1;
    bool vld = n < n_rows;

    float o[16];
    #pragma unroll
    for (int k = 0; k < 16; k++) o[k] = 0.f;

    if (vld) {
        int base = row_start[n];
        int end = row_start[n + 1];
        float adh = a_dst[n * 4 + hd];

        floatx2 acc[8];
        #pragma unroll
        for (int k = 0; k < 8; k++) acc[k] = (floatx2){0.f, 0.f};
        float wsum = 0.f;

        int j = base;
        int head_n = min(end - j, (4 - (base & 3)) & 3);
        for (int q = 0; q < head_n; q++, j++) {
            int s0 = srcs[j];
            float w0 = __expf(leaky(a_src[s0 * 4 + hd] + adh));
            uint4 d0 = *(const uint4*)&H8[(size_t)s0 * 128 + li * 16];
            acc16(acc, w0, d0);
            wsum += w0;
        }
        for (; j + 4 <= end; j += 4) {
            uint2 sv = *(const uint2*)&srcs[j];
            int s0 = sv.x & 0xFFFFu, s1 = sv.x >> 16;
            int s2 = sv.y & 0xFFFFu, s3 = sv.y >> 16;
            float a0 = a_src[s0 * 4 + hd];
            float a1 = a_src[s1 * 4 + hd];
            float a2 = a_src[s2 * 4 + hd];
            float a3 = a_src[s3 * 4 + hd];
            uint4 d0 = *(const uint4*)&H8[(size_t)s0 * 128 + li * 16];
            uint4 d1 = *(const uint4*)&H8[(size_t)s1 * 128 + li * 16];
            uint4 d2 = *(const uint4*)&H8[(size_t)s2 * 128 + li * 16];
            uint4 d3 = *(const uint4*)&H8[(size_t)s3 * 128 + li * 16];
            float w0 = __expf(leaky(a0 + adh));
            float w1 = __expf(leaky(a1 + adh));
            float w2 = __expf(leaky(a2 + adh));
            float w3 = __expf(leaky(a3 + adh));
            acc16(acc, w0, d0);
            acc16(acc, w1, d1);
            acc16(acc, w2, d2);
            acc16(acc, w3, d3);
            wsum += (w0 + w1) + (w2 + w3);
        }
        for (; j < end; j++) {
            int s0 = srcs[j];
            float w0 = __expf(leaky(a_src[s0 * 4 + hd] + adh));
            uint4 d0 = *(const uint4*)&H8[(size_t)s0 * 128 + li * 16];
            acc16(acc, w0, d0);
            wsum += w0;
        }

        float ih = 1.0f / (wsum + 1e-16f);
        #pragma unroll
        for (int k = 0; k < 8; k++) {
            float2 bv = *(const float2*)&bias[li * 16 + 2 * k];
            o[2 * k]     = acc[k].x * ih + bv.x;
            o[2 * k + 1] = acc[k].y * ih + bv.y;
        }
    }

    if (mode == 0) {
        if (vld) {
            #pragma unroll
            for (int k = 0; k < 16; k++) o[k] = o[k] > 0.f ? o[k] : __expf(o[k]) - 1.f;
            unsigned int pk[8];
            #pragma unroll
            for (int k = 0; k < 8; k++)
                pk[k] = ((unsigned)f2bf(o[2 * k + 1]) << 16) | (unsigned)f2bf(o[2 * k]);
            uint4 s0v = {pk[0], pk[1], pk[2], pk[3]};
            uint4 s1v = {pk[4], pk[5], pk[6], pk[7]};
            unsigned short* op = &OUT[(size_t)n * 128 + li * 16];
            *(uint4*)op = s0v;
            *(uint4*)(op + 8) = s1v;
        }
    } else {
        // block-local pool (no atomics): stage 32 node rows, reduce per graph slot
        int nl = threadIdx.x >> 3;
        int n0b = blockIdx.x * 32;
        float* row = &ls[nl][li * 16];
        *(float4*)&row[0]  = (float4){o[0], o[1], o[2], o[3]};
        *(float4*)&row[4]  = (float4){o[4], o[5], o[6], o[7]};
        *(float4*)&row[8]  = (float4){o[8], o[9], o[10], o[11]};
        *(float4*)&row[12] = (float4){o[12], o[13], o[14], o[15]};
        if (li == 0) sg[nl] = vld ? min(batch[n] - batch[n0b], 3) : 0;
        __syncthreads();
        int t = threadIdx.x;
        if (t < 128) {
            float a0 = 0.f, a1 = 0.f, a2 = 0.f, a3 = 0.f;
            #pragma unroll 8
            for (int r = 0; r < 32; r++) {
                float v = ls[r][t];
                int gr = sg[r];
                a0 += (gr == 0) ? v : 0.f;
                a1 += (gr == 1) ? v : 0.f;
                a2 += (gr == 2) ? v : 0.f;
                a3 += (gr == 3) ? v : 0.f;
            }
            float* pp = &partial[(size_t)blockIdx.x * 4 * 128];
            pp[t] = a0;
            pp[128 + t] = a1;
            pp[256 + t] = a2;
            pp[384 + t] = a3;
        }
    }
}

// ---------------- final: gather block partials, mean, fc + log_softmax ----------------
__global__ __launch_bounds__(64) void head_k(const float* __restrict__ partial,
                                             const int* __restrict__ node_end,
                                             const int* __restrict__ batch,
                                             const float* __restrict__ fcW,
                                             const float* __restrict__ fcb,
                                             float* __restrict__ out, int n_rows) {
    __shared__ float p[128];
    __shared__ float lg[8];
    int g = blockIdx.x, t = threadIdx.x;
    int s = (g > 0) ? node_end[g - 1] : 0;
    int e = node_end[g];
    float cnt = fmaxf((float)(e - s), 1.0f);
    float v0 = 0.f, v1 = 0.f;
    if (e > s) {
        int b0 = s >> 5;
        int b1 = (e - 1) >> 5;
        for (int b = b0; b <= b1; b++) {
            int slot = g - batch[b * 32];
            if (slot < 0 || slot > 3) continue;
            const float* pp = &partial[((size_t)b * 4 + slot) * 128];
            v0 += pp[t];
            v1 += pp[64 + t];
        }
    }
    p[t] = v0 / cnt;
    p[t + 64] = v1 / cnt;
    __syncthreads();
    if (t < 8) {
        float sacc = fcb[t];
        for (int k = 0; k < 128; k++) sacc += p[k] * fcW[k * 8 + t];
        lg[t] = sacc;
    }
    __syncthreads();
    if (t == 0) {
        float m = lg[0];
        for (int j = 1; j < 8; j++) m = fmaxf(m, lg[j]);
        float se = 0.f;
        for (int j = 0; j < 8; j++) se += expf(lg[j] - m);
        float lse = logf(se) + m;
        for (int j = 0; j < 8; j++) out[g * 8 + j] = lg[j] - lse;
    }
}

extern "C" void kernel_launch(void* const* d_in, const int* in_sizes, int n_in,
                              void* d_out, int out_size, void* d_ws, size_t ws_size,
                              hipStream_t stream) {
    const float* x    = (const float*)d_in[0];
    const int*   ei   = (const int*)d_in[1];
    const int*   batch= (const int*)d_in[2];
    const float* W1   = (const float*)d_in[3];
    const float* as1  = (const float*)d_in[4];
    const float* ad1  = (const float*)d_in[5];
    const float* b1   = (const float*)d_in[6];
    const float* W2   = (const float*)d_in[7];
    const float* as2  = (const float*)d_in[8];
    const float* ad2  = (const float*)d_in[9];
    const float* b2   = (const float*)d_in[10];
    const float* fcW  = (const float*)d_in[11];
    const float* fcb  = (const float*)d_in[12];
    float* out = (float*)d_out;

    const int Nn = in_sizes[0] / HC;       // 50000
    const int E  = in_sizes[1] / 2;        // 1600000
    const int M  = E + Nn;                 // edges incl. self loops
    const int NB = (Nn + BW - 1) / BW;     // 391 buckets
    const int NBIN = (M + TILE - 1) / TILE;    // binscat blocks (202)
    const int GB1 = (Nn + 63) / 64;            // gemm blocks (782)
    const int NBLK2 = (Nn + 31) / 32;          // agg blocks (1563)

    char* ws = (char*)d_ws;
    size_t off = 0;
    auto alloc = [&](size_t bytes) -> char* {
        char* p = ws + off;
        off = (off + bytes + 255) & ~(size_t)255;
        return p;
    };
    size_t hB_bytes  = (size_t)Nn * HC * 2;     // bf16 node features
    size_t stg_bytes = (size_t)NB * SLOT * 4;   // CSR staging
    char* hB_region = alloc(hB_bytes > stg_bytes ? hB_bytes : stg_bytes);
    unsigned short* hB      = (unsigned short*)hB_region;     // bf16 agg1 out / gemm2 in
    unsigned int*   staging = (unsigned int*)hB_region;       // aliased: used before hB
    unsigned char*  H8      = (unsigned char*)alloc((size_t)Nn * HC);  // fp8 h
    float* asrc      = (float*)alloc((size_t)Nn * 4 * 4);
    float* adst      = (float*)alloc((size_t)Nn * 4 * 4);
    unsigned short* srcs = (unsigned short*)alloc((size_t)M * 2);
    int*   row_start = (int*)alloc((size_t)(Nn + 1) * 4);
    float* partial   = (float*)alloc((size_t)NBLK2 * 4 * HC * 4);
    int*   node_end  = (int*)alloc((size_t)GG * 4);
    int*   gbcur     = (int*)alloc((size_t)NB * 4);
    unsigned short* Wt1 = (unsigned short*)alloc(16384 * 2);
    unsigned short* Wt2 = (unsigned short*)alloc(16384 * 2);

    // 1. setup (gbcur bases + prep_w + bounds + row_start[Nn])
    setup_k<<<(Nn + 255) / 256, 256, 0, stream>>>(W1, W2, Wt1, Wt2, gbcur, batch,
                                                  node_end, row_start, NB, Nn, M);
    // 2. fused: CSR binned scatter ∥ gemm layer-1
    fused_k<<<NBIN + GB1, 256, 0, stream>>>(ei, gbcur, staging, E, M, NB, NBIN,
                                            x, Wt1, as1, ad1, H8, asrc, adst, Nn);
    unbin_k<<<NB, 256, 0, stream>>>(staging, gbcur, row_start, srcs, Nn);
    // 3. layer 1 aggregation (elu + bf16 hB)
    gat_agg<<<NBLK2, 256, 0, stream>>>(H8, asrc, adst, row_start, srcs, b1, hB,
                                       batch, partial, Nn, 0);
    // 4. layer 2
    gemm_fused<<<GB1, 128, 0, stream>>>(hB, Wt2, as2, ad2, H8, asrc, adst, Nn);
    gat_agg<<<NBLK2, 256, 0, stream>>>(H8, asrc, adst, row_start, srcs, b2, hB,
                                       batch, partial, Nn, 1);
    // 5. head (gathers per-block pool partials)
    head_k<<<GG, 64, 0, stream>>>(partial, node_end, batch, fcW, fcb, out, Nn);
}